// Round 4
// baseline (1649.124 us; speedup 1.0000x reference)
//
#include <hip/hip_runtime.h>

typedef unsigned short u16;
typedef __attribute__((ext_vector_type(8))) short s8v;   // 8 x bf16 (4 VGPRs)
typedef __attribute__((ext_vector_type(4))) float f4v;   // MFMA acc

#define MFMA16(a, b, c) __builtin_amdgcn_mfma_f32_16x16x32_bf16(a, b, c, 0, 0, 0)

#define B_    2
#define L_    2048
#define D_    2048
#define H_    16
#define KVH_  4
#define HD_   128
#define F_    5632
#define FC_   1408        // F chunk (4 chunks)
#define MTOK  (B_ * L_)   // 4096
#define NEG_BIG (-1e30f)

__device__ __forceinline__ float b2f(u16 h) {
  union { float f; unsigned u; } v; v.u = ((unsigned)h) << 16; return v.f;
}
__device__ __forceinline__ u16 f2b(float f) {
  union { float f; unsigned u; } v; v.f = f;
  unsigned r = v.u + 0x7FFFu + ((v.u >> 16) & 1u);
  return (u16)(r >> 16);
}
__device__ __forceinline__ s8v ld8(const u16* p) { return *reinterpret_cast<const s8v*>(p); }
__device__ __forceinline__ void st8(u16* p, s8v v) { *reinterpret_cast<s8v*>(p) = v; }

// ---------------- RMSNorm: fp32 in -> bf16 out, one block per row ---------
__global__ __launch_bounds__(256) void rmsnorm_k(const float* __restrict__ x,
                                                 const float* __restrict__ w,
                                                 u16* __restrict__ out) {
  const int row = blockIdx.x, t = threadIdx.x;
  const float* xr = x + (size_t)row * D_ + t * 8;
  float4 a = *(const float4*)(xr);
  float4 b = *(const float4*)(xr + 4);
  float f[8] = {a.x, a.y, a.z, a.w, b.x, b.y, b.z, b.w};
  float ss = 0.f;
#pragma unroll
  for (int j = 0; j < 8; ++j) ss += f[j] * f[j];
#pragma unroll
  for (int m = 1; m < 64; m <<= 1) ss += __shfl_xor(ss, m);
  __shared__ float red[4];
  if ((t & 63) == 0) red[t >> 6] = ss;
  __syncthreads();
  float tot = red[0] + red[1] + red[2] + red[3];
  float inv = rsqrtf(tot * (1.f / D_) + 1e-6f);
  float4 wa = *(const float4*)(w + t * 8);
  float4 wb = *(const float4*)(w + t * 8 + 4);
  float wf[8] = {wa.x, wa.y, wa.z, wa.w, wb.x, wb.y, wb.z, wb.w};
  s8v o;
#pragma unroll
  for (int j = 0; j < 8; ++j) o[j] = (short)f2b(f[j] * inv * wf[j]);
  st8(out + (size_t)row * D_ + t * 8, o);
}

// ---------------- NT GEMM: C[M,N] = A_bf16[M,:K] * W_f32[N,:K]^T ----------
// W staged fp32->bf16. optional fp32 +bias, fp32 +resid, bf16 *silu(gatein).
// C is bf16 (C_F32=false) or fp32 (C_F32=true).
// 128x128 tile, BK=32, 256 threads (4 waves, 2x2 of 64x64), mfma 16x16x32 bf16
template <bool C_F32>
__global__ __launch_bounds__(256) void gemm_nt(const u16* __restrict__ A, int lda,
                                               const float* __restrict__ W, int ldw,
                                               const float* __restrict__ bias,
                                               const float* resid,
                                               const u16* gatein,
                                               void* Cv,
                                               int M, int N, int K) {
  __shared__ __align__(16) u16 As[128 * 32];
  __shared__ __align__(16) u16 Bs[128 * 32];
  const int t = threadIdx.x;
  const int l = t & 63, w = t >> 6;
  const int lr = l & 15, lg = l >> 4;
  const int m0 = blockIdx.y * 128, n0 = blockIdx.x * 128;
  const int wm = (w >> 1) * 64, wn = (w & 1) * 64;
  const int sr = t >> 2, sc = (t & 3) * 8;
  const u16* Ag0 = A + (size_t)(m0 + sr) * lda + sc;
  const u16* Ag1 = A + (size_t)(m0 + sr + 64) * lda + sc;
  const float* Wg0 = W + (size_t)(n0 + sr) * ldw + sc;
  const float* Wg1 = W + (size_t)(n0 + sr + 64) * ldw + sc;

  const f4v zero4 = {0.f, 0.f, 0.f, 0.f};
  f4v acc[4][4];
#pragma unroll
  for (int i = 0; i < 4; ++i)
#pragma unroll
    for (int j = 0; j < 4; ++j) acc[i][j] = zero4;

  for (int k0 = 0; k0 < K; k0 += 32) {
    s8v a0 = ld8(Ag0 + k0), a1 = ld8(Ag1 + k0);
    float4 w0a = *(const float4*)(Wg0 + k0), w0b = *(const float4*)(Wg0 + k0 + 4);
    float4 w1a = *(const float4*)(Wg1 + k0), w1b = *(const float4*)(Wg1 + k0 + 4);
    float wf0[8] = {w0a.x, w0a.y, w0a.z, w0a.w, w0b.x, w0b.y, w0b.z, w0b.w};
    float wf1[8] = {w1a.x, w1a.y, w1a.z, w1a.w, w1b.x, w1b.y, w1b.z, w1b.w};
    s8v b0, b1;
#pragma unroll
    for (int j = 0; j < 8; ++j) { b0[j] = (short)f2b(wf0[j]); b1[j] = (short)f2b(wf1[j]); }
    __syncthreads();
    st8(&As[sr * 32 + sc], a0);
    st8(&As[(sr + 64) * 32 + sc], a1);
    st8(&Bs[sr * 32 + sc], b0);
    st8(&Bs[(sr + 64) * 32 + sc], b1);
    __syncthreads();
    s8v af[4], bf[4];
#pragma unroll
    for (int i = 0; i < 4; ++i) {
      af[i] = ld8(&As[(wm + i * 16 + lr) * 32 + lg * 8]);
      bf[i] = ld8(&Bs[(wn + i * 16 + lr) * 32 + lg * 8]);
    }
#pragma unroll
    for (int i = 0; i < 4; ++i)
#pragma unroll
      for (int j = 0; j < 4; ++j)
        acc[i][j] = MFMA16(af[i], bf[j], acc[i][j]);
  }
  // epilogue: C/D layout col = lane&15, row = (lane>>4)*4 + reg  [m89-verified]
#pragma unroll
  for (int j = 0; j < 4; ++j) {
    const int col = n0 + wn + j * 16 + lr;
    const float bv = bias ? bias[col] : 0.f;
#pragma unroll
    for (int i = 0; i < 4; ++i) {
      const int row = m0 + wm + i * 16 + lg * 4;
#pragma unroll
      for (int r = 0; r < 4; ++r) {
        float vv = acc[i][j][r] + bv;
        size_t off = (size_t)(row + r) * N + col;
        if (gatein) {
          float gf = b2f(gatein[off]);
          vv *= gf / (1.f + __expf(-gf));   // silu(gate) * up
        }
        if (resid) vv += resid[off];
        if (C_F32) ((float*)Cv)[off] = vv;
        else       ((u16*)Cv)[off]   = f2b(vv);
      }
    }
  }
}

// ---------------- V transpose: bf16 [B,L,512] -> VT [B][KVH][HD][L] -------
__global__ __launch_bounds__(256) void transpose_v(const u16* __restrict__ V,
                                                   u16* __restrict__ VT) {
  __shared__ u16 tile[64][72];
  const int t = threadIdx.x;
  const int tok0 = blockIdx.x * 64;
  const int hd0 = blockIdx.y * 64;
  const int bk = blockIdx.z;           // b*KVH + kvh
  const int b = bk >> 2, kvh = bk & 3;
#pragma unroll
  for (int c = 0; c < 16; ++c) {
    int idx = t + c * 256;
    int tok = idx >> 6, hd = idx & 63;
    tile[tok][hd] = V[(size_t)(b * L_ + tok0 + tok) * 512 + kvh * 128 + hd0 + hd];
  }
  __syncthreads();
#pragma unroll
  for (int c = 0; c < 16; ++c) {
    int idx = t + c * 256;
    int tok = idx & 63, hd = idx >> 6;
    VT[(size_t)(bk * 128 + hd0 + hd) * L_ + tok0 + tok] = tile[tok][hd];
  }
}

// ---------------- Flash attention, causal, GQA (kv = h % 4), all bf16 -----
__global__ __launch_bounds__(256) void attn_k(const u16* __restrict__ Q,
                                              const u16* __restrict__ Kx,
                                              const u16* __restrict__ VT,
                                              u16* __restrict__ O) {
  __shared__ __align__(16) u16 Kt[64 * 136];     // [key][hd], stride 136
  __shared__ __align__(16) u16 Vtl[128 * 72];    // [hd][key], stride 72
  __shared__ __align__(16) u16 Pb[4 * 32 * 72];  // per-wave [qlocal][key], stride 72
  const int t = threadIdx.x, l = t & 63, w = t >> 6;
  const int lr = l & 15, lg = l >> 4;
  const int bh = blockIdx.y, b = bh >> 4, h = bh & 15, kvh = h & 3;
  const int q0 = blockIdx.x * 128;
  const f4v zero4 = {0.f, 0.f, 0.f, 0.f};

  // Q fragments (A-layout: m = lane&15, k = (lane>>4)*8+j)
  s8v qf[2][4];
#pragma unroll
  for (int mf = 0; mf < 2; ++mf)
#pragma unroll
    for (int kf = 0; kf < 4; ++kf)
      qf[mf][kf] = ld8(Q + (size_t)(b * L_ + q0 + w * 32 + mf * 16 + lr) * 2048 +
                       h * 128 + kf * 32 + lg * 8);

  float mrow[2][4], srow[2][4];
  f4v oacc[2][8];
#pragma unroll
  for (int mf = 0; mf < 2; ++mf) {
#pragma unroll
    for (int r = 0; r < 4; ++r) { mrow[mf][r] = NEG_BIG; srow[mf][r] = 0.f; }
#pragma unroll
    for (int n = 0; n < 8; ++n) oacc[mf][n] = zero4;
  }
  u16* Pw = Pb + w * 32 * 72;
  const float scale = 0.08838834764831845f;  // 128^-0.5
  const int ktmax = q0 / 64 + 1;

  for (int kt = 0; kt <= ktmax; ++kt) {
    __syncthreads();  // previous iteration's LDS reads complete
    // stage K tile: 64 keys x 128 hd
#pragma unroll
    for (int c = 0; c < 4; ++c) {
      int id = t + c * 256;
      int row = id >> 4, c8 = (id & 15) * 8;
      s8v kv = ld8(Kx + (size_t)(b * L_ + kt * 64 + row) * 512 + kvh * 128 + c8);
      st8(&Kt[row * 136 + c8], kv);
    }
    // stage V^T tile: 128 hd x 64 keys
#pragma unroll
    for (int c = 0; c < 4; ++c) {
      int id = t + c * 256;
      int row = id >> 3, c8 = (id & 7) * 8;
      s8v vv = ld8(VT + (size_t)((b * 4 + kvh) * 128 + row) * L_ + kt * 64 + c8);
      st8(&Vtl[row * 72 + c8], vv);
    }
    __syncthreads();

    // S = Q K^T
    f4v s[2][4];
#pragma unroll
    for (int mf = 0; mf < 2; ++mf)
#pragma unroll
      for (int nf = 0; nf < 4; ++nf) s[mf][nf] = zero4;
#pragma unroll
    for (int nf = 0; nf < 4; ++nf)
#pragma unroll
      for (int kf = 0; kf < 4; ++kf) {
        s8v bfr = ld8(&Kt[(nf * 16 + lr) * 136 + kf * 32 + lg * 8]);
#pragma unroll
        for (int mf = 0; mf < 2; ++mf) s[mf][nf] = MFMA16(qf[mf][kf], bfr, s[mf][nf]);
      }

    const bool needmask = (kt * 64 + 63) > q0;
#pragma unroll
    for (int mf = 0; mf < 2; ++mf)
#pragma unroll
      for (int nf = 0; nf < 4; ++nf)
#pragma unroll
        for (int r = 0; r < 4; ++r) {
          float vv = s[mf][nf][r] * scale;
          if (needmask) {
            int key = kt * 64 + nf * 16 + lr;
            int qr = q0 + w * 32 + mf * 16 + lg * 4 + r;
            if (key > qr) vv = NEG_BIG;
          }
          s[mf][nf][r] = vv;
        }

    // row max over tile
    float tm[2][4];
#pragma unroll
    for (int mf = 0; mf < 2; ++mf)
#pragma unroll
      for (int r = 0; r < 4; ++r) {
        float m = NEG_BIG;
#pragma unroll
        for (int nf = 0; nf < 4; ++nf) m = fmaxf(m, s[mf][nf][r]);
#pragma unroll
        for (int msk = 1; msk < 16; msk <<= 1) m = fmaxf(m, __shfl_xor(m, msk));
        tm[mf][r] = m;
      }
    float al[2][4];
#pragma unroll
    for (int mf = 0; mf < 2; ++mf)
#pragma unroll
      for (int r = 0; r < 4; ++r) {
        float mn = fmaxf(mrow[mf][r], tm[mf][r]);
        al[mf][r] = __expf(mrow[mf][r] - mn);
        mrow[mf][r] = mn;
      }
    // P = exp(S - m), row sums, write P (bf16) to per-wave LDS
    float rs[2][4];
#pragma unroll
    for (int mf = 0; mf < 2; ++mf)
#pragma unroll
      for (int r = 0; r < 4; ++r) rs[mf][r] = 0.f;
#pragma unroll
    for (int mf = 0; mf < 2; ++mf)
#pragma unroll
      for (int nf = 0; nf < 4; ++nf)
#pragma unroll
        for (int r = 0; r < 4; ++r) {
          float p = __expf(s[mf][nf][r] - mrow[mf][r]);
          rs[mf][r] += p;
          Pw[(mf * 16 + lg * 4 + r) * 72 + nf * 16 + lr] = f2b(p);
        }
    __syncthreads();  // P write -> P A-frag read ordering
#pragma unroll
    for (int mf = 0; mf < 2; ++mf)
#pragma unroll
      for (int r = 0; r < 4; ++r) {
#pragma unroll
        for (int msk = 1; msk < 16; msk <<= 1) rs[mf][r] += __shfl_xor(rs[mf][r], msk);
        srow[mf][r] = srow[mf][r] * al[mf][r] + rs[mf][r];
      }
#pragma unroll
    for (int mf = 0; mf < 2; ++mf)
#pragma unroll
      for (int n = 0; n < 8; ++n)
#pragma unroll
        for (int r = 0; r < 4; ++r) oacc[mf][n][r] *= al[mf][r];

    // O += P V
    s8v pa[2][2];
#pragma unroll
    for (int mf = 0; mf < 2; ++mf)
#pragma unroll
      for (int k2 = 0; k2 < 2; ++k2)
        pa[mf][k2] = ld8(&Pw[(mf * 16 + lr) * 72 + k2 * 32 + lg * 8]);
#pragma unroll
    for (int n = 0; n < 8; ++n)
#pragma unroll
      for (int k2 = 0; k2 < 2; ++k2) {
        s8v vb = ld8(&Vtl[(n * 16 + lr) * 72 + k2 * 32 + lg * 8]);
#pragma unroll
        for (int mf = 0; mf < 2; ++mf) oacc[mf][n] = MFMA16(pa[mf][k2], vb, oacc[mf][n]);
      }
  }

  // normalize + store (bf16)
#pragma unroll
  for (int mf = 0; mf < 2; ++mf)
#pragma unroll
    for (int r = 0; r < 4; ++r) {
      float inv = 1.f / srow[mf][r];
#pragma unroll
      for (int n = 0; n < 8; ++n) {
        size_t off = (size_t)(b * L_ + q0 + w * 32 + mf * 16 + lg * 4 + r) * 2048 +
                     h * 128 + n * 16 + lr;
        O[off] = f2b(oacc[mf][n][r] * inv);
      }
    }
}

// ---------------- launch ---------------------------------------------------
// All d_in / d_out are FP32 (per the reference dtypes). Internals are bf16.
// ws high-water: 27 MiB.
//   h  [ 0,16M)  bf16: rmsnorm1 out -> attn out -> rmsnorm2 out
//   kb [16,20M)  bf16 K (dead after attn)
//   vb [20,24M)  bf16 V (dead after transpose)
//   vt [24,28M)... actually vt shares [24,27M+]: VT is 4 MiB -> [24,28M)
//   g  [16,27M)  bf16 MLP chunk [4096,1408] (11 MiB), reuses kb/vb after attn
// d_out (fp32, 32 MiB): first 16 MiB doubles as bf16 Q scratch (phase A);
// then o-proj writes x2=x+attn@ow fp32 into all of d_out; down chunks
// accumulate via resid=d_out (same-element read->write, no cross-thread alias).
extern "C" void kernel_launch(void* const* d_in, const int* in_sizes, int n_in,
                              void* d_out, int out_size, void* d_ws, size_t ws_size,
                              hipStream_t stream) {
  const float* x    = (const float*)d_in[0];
  const float* ln1w = (const float*)d_in[1];
  const float* qw   = (const float*)d_in[2];
  const float* qb   = (const float*)d_in[3];
  const float* kw   = (const float*)d_in[4];
  const float* kb   = (const float*)d_in[5];
  const float* vw   = (const float*)d_in[6];
  const float* vbi  = (const float*)d_in[7];
  const float* ow   = (const float*)d_in[8];
  const float* ln2w = (const float*)d_in[9];
  const float* gw   = (const float*)d_in[10];
  const float* uw   = (const float*)d_in[11];
  const float* dw   = (const float*)d_in[12];
  float* out = (float*)d_out;

  char* ws = (char*)d_ws;
  u16* h    = (u16*)(ws);                  // 16 MiB
  u16* kbuf = (u16*)(ws + (16ull << 20));  // 4 MiB
  u16* vbuf = (u16*)(ws + (20ull << 20));  // 4 MiB
  u16* vt   = (u16*)(ws + (24ull << 20));  // 4 MiB
  u16* g    = (u16*)(ws + (16ull << 20));  // 11 MiB (phase C, reuses kb/vb)
  u16* qscr = (u16*)d_out;                 // bf16 Q scratch in d_out (16 MiB)

  dim3 blk(256);
  rmsnorm_k<<<MTOK, blk, 0, stream>>>(x, ln1w, h);
  gemm_nt<false><<<dim3(16, 32), blk, 0, stream>>>(h, D_, qw, D_, qb, nullptr, nullptr,
                                                   qscr, MTOK, 2048, 2048);
  gemm_nt<false><<<dim3(4, 32), blk, 0, stream>>>(h, D_, kw, D_, kb, nullptr, nullptr,
                                                  kbuf, MTOK, 512, 2048);
  gemm_nt<false><<<dim3(4, 32), blk, 0, stream>>>(h, D_, vw, D_, vbi, nullptr, nullptr,
                                                  vbuf, MTOK, 512, 2048);
  transpose_v<<<dim3(32, 2, 8), blk, 0, stream>>>(vbuf, vt);
  attn_k<<<dim3(16, 32), blk, 0, stream>>>(qscr, kbuf, vt, h);  // h <- attn out
  // o-proj: d_out = attn @ ow^T + x   (fp32; Q scratch dead)
  gemm_nt<true><<<dim3(16, 32), blk, 0, stream>>>(h, D_, ow, D_, nullptr, x, nullptr,
                                                  d_out, MTOK, 2048, 2048);
  rmsnorm_k<<<MTOK, blk, 0, stream>>>(out, ln2w, h);            // h <- h2
  for (int fc = 0; fc < 4; ++fc) {
    const float* gwc = gw + (size_t)fc * FC_ * D_;
    const float* uwc = uw + (size_t)fc * FC_ * D_;
    const float* dwc = dw + (size_t)fc * FC_;
    gemm_nt<false><<<dim3(11, 32), blk, 0, stream>>>(h, D_, gwc, D_, nullptr, nullptr,
                                                     nullptr, g, MTOK, FC_, 2048);
    gemm_nt<false><<<dim3(11, 32), blk, 0, stream>>>(h, D_, uwc, D_, nullptr, nullptr,
                                                     g, g, MTOK, FC_, 2048);
    gemm_nt<true><<<dim3(16, 32), blk, 0, stream>>>(g, FC_, dwc, F_, nullptr, out,
                                                    nullptr, d_out, MTOK, 2048, FC_);
  }
}

// Round 5
// 1506.590 us; speedup vs baseline: 1.0946x; 1.0946x over previous
//
#include <hip/hip_runtime.h>

typedef unsigned short u16;
typedef __attribute__((ext_vector_type(8))) short s8v;   // 8 x bf16 (4 VGPRs)
typedef __attribute__((ext_vector_type(4))) float f4v;   // MFMA acc

#define MFMA16(a, b, c) __builtin_amdgcn_mfma_f32_16x16x32_bf16(a, b, c, 0, 0, 0)

#define B_    2
#define L_    2048
#define D_    2048
#define H_    16
#define KVH_  4
#define HD_   128
#define F_    5632
#define FC_   1408        // F chunk (4 chunks)
#define MTOK  (B_ * L_)   // 4096
#define NEG_BIG (-1e30f)
#define SCL2E 0.127517416f   // 128^-0.5 * log2(e)

__device__ __forceinline__ float b2f(u16 h) {
  union { float f; unsigned u; } v; v.u = ((unsigned)h) << 16; return v.f;
}
__device__ __forceinline__ u16 f2b(float f) {
  union { float f; unsigned u; } v; v.f = f;
  unsigned r = v.u + 0x7FFFu + ((v.u >> 16) & 1u);
  return (u16)(r >> 16);
}
__device__ __forceinline__ s8v ld8(const u16* p) { return *reinterpret_cast<const s8v*>(p); }
__device__ __forceinline__ void st8(u16* p, s8v v) { *reinterpret_cast<s8v*>(p) = v; }
// async global->LDS, 16B per lane; lds dest = wave-uniform base + lane*16 [m97]
__device__ __forceinline__ void gld16(const u16* g, u16* l) {
  __builtin_amdgcn_global_load_lds((const __attribute__((address_space(1))) void*)g,
                                   (__attribute__((address_space(3))) void*)l, 16, 0, 0);
}

// ---------------- fp32 -> bf16 weight convert (grid-stride, 8/thread) -----
__global__ __launch_bounds__(256) void conv_k(const float* __restrict__ src,
                                              u16* __restrict__ dst, int n8) {
  int i = blockIdx.x * 256 + threadIdx.x;
  const int stride = gridDim.x * 256;
  for (; i < n8; i += stride) {
    const float* p = src + (size_t)i * 8;
    float4 a = *(const float4*)p, b = *(const float4*)(p + 4);
    float f[8] = {a.x, a.y, a.z, a.w, b.x, b.y, b.z, b.w};
    s8v o;
#pragma unroll
    for (int j = 0; j < 8; ++j) o[j] = (short)f2b(f[j]);
    st8(dst + (size_t)i * 8, o);
  }
}

// ---------------- RMSNorm: fp32 in -> bf16 out, one block per row ---------
__global__ __launch_bounds__(256) void rmsnorm_k(const float* __restrict__ x,
                                                 const float* __restrict__ w,
                                                 u16* __restrict__ out) {
  const int row = blockIdx.x, t = threadIdx.x;
  const float* xr = x + (size_t)row * D_ + t * 8;
  float4 a = *(const float4*)(xr);
  float4 b = *(const float4*)(xr + 4);
  float f[8] = {a.x, a.y, a.z, a.w, b.x, b.y, b.z, b.w};
  float ss = 0.f;
#pragma unroll
  for (int j = 0; j < 8; ++j) ss += f[j] * f[j];
#pragma unroll
  for (int m = 1; m < 64; m <<= 1) ss += __shfl_xor(ss, m);
  __shared__ float red[4];
  if ((t & 63) == 0) red[t >> 6] = ss;
  __syncthreads();
  float tot = red[0] + red[1] + red[2] + red[3];
  float inv = rsqrtf(tot * (1.f / D_) + 1e-6f);
  float4 wa = *(const float4*)(w + t * 8);
  float4 wb = *(const float4*)(w + t * 8 + 4);
  float wf[8] = {wa.x, wa.y, wa.z, wa.w, wb.x, wb.y, wb.z, wb.w};
  s8v o;
#pragma unroll
  for (int j = 0; j < 8; ++j) o[j] = (short)f2b(f[j] * inv * wf[j]);
  st8(out + (size_t)row * D_ + t * 8, o);
}

// ======== GEMM variant 1: A bf16, W bf16, global_load_lds staging =========
// C[M,N] = A[M,:K] * W[N,:K]^T ; m97-style 2-barrier K-loop.
template <bool C_F32>
__global__ __launch_bounds__(256) void gemm_bb(const u16* __restrict__ A, int lda,
                                               const u16* __restrict__ W, int ldw,
                                               const float* __restrict__ bias,
                                               const float* resid,
                                               const u16* gatein,
                                               void* Cv,
                                               int M, int N, int K) {
  __shared__ __align__(16) u16 As[128 * 32];
  __shared__ __align__(16) u16 Bs[128 * 32];
  const int t = threadIdx.x;
  const int l = t & 63, w = t >> 6;
  const int lr = l & 15, lg = l >> 4;
  const int m0 = blockIdx.y * 128, n0 = blockIdx.x * 128;
  const int wm = (w >> 1) * 64, wn = (w & 1) * 64;
  const int sr = t >> 2, sc = (t & 3) * 8;
  const u16* Ag0 = A + (size_t)(m0 + sr) * lda + sc;
  const u16* Ag1 = A + (size_t)(m0 + sr + 64) * lda + sc;
  const u16* Wg0 = W + (size_t)(n0 + sr) * ldw + sc;
  const u16* Wg1 = W + (size_t)(n0 + sr + 64) * ldw + sc;
  // wave-uniform LDS bases: thread t's 16B slot is at linear offset t*8 u16
  u16* As0 = &As[w * 512]; u16* As1 = &As[2048 + w * 512];
  u16* Bs0 = &Bs[w * 512]; u16* Bs1 = &Bs[2048 + w * 512];

  const f4v zero4 = {0.f, 0.f, 0.f, 0.f};
  f4v acc[4][4];
#pragma unroll
  for (int i = 0; i < 4; ++i)
#pragma unroll
    for (int j = 0; j < 4; ++j) acc[i][j] = zero4;

  for (int k0 = 0; k0 < K; k0 += 32) {
    __syncthreads();                       // prev iter's ds_reads done
    gld16(Ag0 + k0, As0);
    gld16(Ag1 + k0, As1);
    gld16(Wg0 + k0, Bs0);
    gld16(Wg1 + k0, Bs1);
    __syncthreads();                       // drains vmcnt -> LDS valid
    s8v af[4], bf[4];
#pragma unroll
    for (int i = 0; i < 4; ++i) {
      af[i] = ld8(&As[(wm + i * 16 + lr) * 32 + lg * 8]);
      bf[i] = ld8(&Bs[(wn + i * 16 + lr) * 32 + lg * 8]);
    }
#pragma unroll
    for (int i = 0; i < 4; ++i)
#pragma unroll
      for (int j = 0; j < 4; ++j)
        acc[i][j] = MFMA16(af[i], bf[j], acc[i][j]);
  }
  // epilogue: C/D layout col = lane&15, row = (lane>>4)*4 + reg  [m89]
#pragma unroll
  for (int j = 0; j < 4; ++j) {
    const int col = n0 + wn + j * 16 + lr;
    const float bv = bias ? bias[col] : 0.f;
#pragma unroll
    for (int i = 0; i < 4; ++i) {
      const int row = m0 + wm + i * 16 + lg * 4;
#pragma unroll
      for (int r = 0; r < 4; ++r) {
        float vv = acc[i][j][r] + bv;
        size_t off = (size_t)(row + r) * N + col;
        if (gatein) {
          float gf = b2f(gatein[off]);
          vv *= gf / (1.f + __expf(-gf));   // silu(gate) * up
        }
        if (resid) vv += resid[off];
        if (C_F32) ((float*)Cv)[off] = vv;
        else       ((u16*)Cv)[off]   = f2b(vv);
      }
    }
  }
}

// ======== GEMM variant 2 (fallback): A bf16, W fp32 staged in regs ========
template <bool C_F32>
__global__ __launch_bounds__(256) void gemm_nt(const u16* __restrict__ A, int lda,
                                               const float* __restrict__ W, int ldw,
                                               const float* __restrict__ bias,
                                               const float* resid,
                                               const u16* gatein,
                                               void* Cv,
                                               int M, int N, int K) {
  __shared__ __align__(16) u16 As[128 * 32];
  __shared__ __align__(16) u16 Bs[128 * 32];
  const int t = threadIdx.x;
  const int l = t & 63, w = t >> 6;
  const int lr = l & 15, lg = l >> 4;
  const int m0 = blockIdx.y * 128, n0 = blockIdx.x * 128;
  const int wm = (w >> 1) * 64, wn = (w & 1) * 64;
  const int sr = t >> 2, sc = (t & 3) * 8;
  const u16* Ag0 = A + (size_t)(m0 + sr) * lda + sc;
  const u16* Ag1 = A + (size_t)(m0 + sr + 64) * lda + sc;
  const float* Wg0 = W + (size_t)(n0 + sr) * ldw + sc;
  const float* Wg1 = W + (size_t)(n0 + sr + 64) * ldw + sc;

  const f4v zero4 = {0.f, 0.f, 0.f, 0.f};
  f4v acc[4][4];
#pragma unroll
  for (int i = 0; i < 4; ++i)
#pragma unroll
    for (int j = 0; j < 4; ++j) acc[i][j] = zero4;

  for (int k0 = 0; k0 < K; k0 += 32) {
    s8v a0 = ld8(Ag0 + k0), a1 = ld8(Ag1 + k0);
    float4 w0a = *(const float4*)(Wg0 + k0), w0b = *(const float4*)(Wg0 + k0 + 4);
    float4 w1a = *(const float4*)(Wg1 + k0), w1b = *(const float4*)(Wg1 + k0 + 4);
    float wf0[8] = {w0a.x, w0a.y, w0a.z, w0a.w, w0b.x, w0b.y, w0b.z, w0b.w};
    float wf1[8] = {w1a.x, w1a.y, w1a.z, w1a.w, w1b.x, w1b.y, w1b.z, w1b.w};
    s8v b0, b1;
#pragma unroll
    for (int j = 0; j < 8; ++j) { b0[j] = (short)f2b(wf0[j]); b1[j] = (short)f2b(wf1[j]); }
    __syncthreads();
    st8(&As[sr * 32 + sc], a0);
    st8(&As[(sr + 64) * 32 + sc], a1);
    st8(&Bs[sr * 32 + sc], b0);
    st8(&Bs[(sr + 64) * 32 + sc], b1);
    __syncthreads();
    s8v af[4], bf[4];
#pragma unroll
    for (int i = 0; i < 4; ++i) {
      af[i] = ld8(&As[(wm + i * 16 + lr) * 32 + lg * 8]);
      bf[i] = ld8(&Bs[(wn + i * 16 + lr) * 32 + lg * 8]);
    }
#pragma unroll
    for (int i = 0; i < 4; ++i)
#pragma unroll
      for (int j = 0; j < 4; ++j)
        acc[i][j] = MFMA16(af[i], bf[j], acc[i][j]);
  }
#pragma unroll
  for (int j = 0; j < 4; ++j) {
    const int col = n0 + wn + j * 16 + lr;
    const float bv = bias ? bias[col] : 0.f;
#pragma unroll
    for (int i = 0; i < 4; ++i) {
      const int row = m0 + wm + i * 16 + lg * 4;
#pragma unroll
      for (int r = 0; r < 4; ++r) {
        float vv = acc[i][j][r] + bv;
        size_t off = (size_t)(row + r) * N + col;
        if (gatein) {
          float gf = b2f(gatein[off]);
          vv *= gf / (1.f + __expf(-gf));
        }
        if (resid) vv += resid[off];
        if (C_F32) ((float*)Cv)[off] = vv;
        else       ((u16*)Cv)[off]   = f2b(vv);
      }
    }
  }
}

// ---------------- V transpose: bf16 [B,L,512] -> VT [B][KVH][HD][L] -------
__global__ __launch_bounds__(256) void transpose_v(const u16* __restrict__ V,
                                                   u16* __restrict__ VT) {
  __shared__ u16 tile[64][72];
  const int t = threadIdx.x;
  const int tok0 = blockIdx.x * 64;
  const int hd0 = blockIdx.y * 64;
  const int bk = blockIdx.z;           // b*KVH + kvh
  const int b = bk >> 2, kvh = bk & 3;
#pragma unroll
  for (int c = 0; c < 16; ++c) {
    int idx = t + c * 256;
    int tok = idx >> 6, hd = idx & 63;
    tile[tok][hd] = V[(size_t)(b * L_ + tok0 + tok) * 512 + kvh * 128 + hd0 + hd];
  }
  __syncthreads();
#pragma unroll
  for (int c = 0; c < 16; ++c) {
    int idx = t + c * 256;
    int tok = idx & 63, hd = idx >> 6;
    VT[(size_t)(bk * 128 + hd0 + hd) * L_ + tok0 + tok] = tile[tok][hd];
  }
}

// ---------------- Flash attention, causal, GQA (kv = h % 4), all bf16 -----
// q-tile 64 (grid 32x32=1024 blocks), 4 waves, wave w owns q rows w*16..+15.
// k-tiles of 64 keys; exp2-domain softmax (logits pre-scaled by log2e).
__global__ __launch_bounds__(256) void attn_k(const u16* __restrict__ Q,
                                              const u16* __restrict__ Kx,
                                              const u16* __restrict__ VT,
                                              u16* __restrict__ O) {
  __shared__ __align__(16) u16 Kt[64 * 136];     // [key][hd], stride 136
  __shared__ __align__(16) u16 Vtl[128 * 72];    // [hd][key], stride 72
  __shared__ __align__(16) u16 Pb[4 * 16 * 72];  // per-wave [qlocal][key]
  const int t = threadIdx.x, l = t & 63, w = t >> 6;
  const int lr = l & 15, lg = l >> 4;
  const int bh = blockIdx.y, b = bh >> 4, h = bh & 15, kvh = h & 3;
  const int q0 = blockIdx.x * 64;
  const f4v zero4 = {0.f, 0.f, 0.f, 0.f};

  // Q fragments (A-layout: m = lane&15, k = (lane>>4)*8+j)
  s8v qf[4];
#pragma unroll
  for (int kf = 0; kf < 4; ++kf)
    qf[kf] = ld8(Q + (size_t)(b * L_ + q0 + w * 16 + lr) * 2048 +
                 h * 128 + kf * 32 + lg * 8);

  float mrow[4], srow[4];
  f4v oacc[8];
#pragma unroll
  for (int r = 0; r < 4; ++r) { mrow[r] = NEG_BIG; srow[r] = 0.f; }
#pragma unroll
  for (int n = 0; n < 8; ++n) oacc[n] = zero4;
  u16* Pw = Pb + w * 16 * 72;
  const int ktmax = blockIdx.x;

  for (int kt = 0; kt <= ktmax; ++kt) {
    __syncthreads();  // previous iteration's LDS reads complete
    // stage K tile: 64 keys x 128 hd
#pragma unroll
    for (int c = 0; c < 4; ++c) {
      int id = t + c * 256;
      int row = id >> 4, c8 = (id & 15) * 8;
      s8v kv = ld8(Kx + (size_t)(b * L_ + kt * 64 + row) * 512 + kvh * 128 + c8);
      st8(&Kt[row * 136 + c8], kv);
    }
    // stage V^T tile: 128 hd x 64 keys
#pragma unroll
    for (int c = 0; c < 4; ++c) {
      int id = t + c * 256;
      int row = id >> 3, c8 = (id & 7) * 8;
      s8v vv = ld8(VT + (size_t)((b * 4 + kvh) * 128 + row) * L_ + kt * 64 + c8);
      st8(&Vtl[row * 72 + c8], vv);
    }
    __syncthreads();

    // S = Q K^T  (1 mf x 4 nf, K=128 via 4 kf)
    f4v s[4];
#pragma unroll
    for (int nf = 0; nf < 4; ++nf) s[nf] = zero4;
#pragma unroll
    for (int nf = 0; nf < 4; ++nf)
#pragma unroll
      for (int kf = 0; kf < 4; ++kf) {
        s8v bfr = ld8(&Kt[(nf * 16 + lr) * 136 + kf * 32 + lg * 8]);
        s[nf] = MFMA16(qf[kf], bfr, s[nf]);
      }

    const bool needmask = (kt == ktmax);
#pragma unroll
    for (int nf = 0; nf < 4; ++nf)
#pragma unroll
      for (int r = 0; r < 4; ++r) {
        float vv = s[nf][r] * SCL2E;
        if (needmask) {
          int key = kt * 64 + nf * 16 + lr;
          int qr = q0 + w * 16 + lg * 4 + r;
          if (key > qr) vv = NEG_BIG;
        }
        s[nf][r] = vv;
      }

    // row max (16 lr-lanes x 4 nf)
    float tm[4];
#pragma unroll
    for (int r = 0; r < 4; ++r) {
      float m = fmaxf(fmaxf(s[0][r], s[1][r]), fmaxf(s[2][r], s[3][r]));
#pragma unroll
      for (int msk = 1; msk < 16; msk <<= 1) m = fmaxf(m, __shfl_xor(m, msk));
      tm[r] = m;
    }
    float al[4], rs[4];
#pragma unroll
    for (int r = 0; r < 4; ++r) {
      float mn = fmaxf(mrow[r], tm[r]);
      al[r] = exp2f(mrow[r] - mn);
      mrow[r] = mn;
      rs[r] = 0.f;
    }
    // P = exp2(S - m); bf16 P to per-wave LDS (wave-private, in-order DS)
#pragma unroll
    for (int nf = 0; nf < 4; ++nf)
#pragma unroll
      for (int r = 0; r < 4; ++r) {
        float p = exp2f(s[nf][r] - mrow[r]);
        rs[r] += p;
        Pw[(lg * 4 + r) * 72 + nf * 16 + lr] = f2b(p);
      }
#pragma unroll
    for (int r = 0; r < 4; ++r) {
#pragma unroll
      for (int msk = 1; msk < 16; msk <<= 1) rs[r] += __shfl_xor(rs[r], msk);
      srow[r] = srow[r] * al[r] + rs[r];
    }
#pragma unroll
    for (int n = 0; n < 8; ++n)
#pragma unroll
      for (int r = 0; r < 4; ++r) oacc[n][r] *= al[r];

    // O += P V
    s8v pa[2];
#pragma unroll
    for (int k2 = 0; k2 < 2; ++k2)
      pa[k2] = ld8(&Pw[lr * 72 + k2 * 32 + lg * 8]);
#pragma unroll
    for (int n = 0; n < 8; ++n)
#pragma unroll
      for (int k2 = 0; k2 < 2; ++k2) {
        s8v vb = ld8(&Vtl[(n * 16 + lr) * 72 + k2 * 32 + lg * 8]);
        oacc[n] = MFMA16(pa[k2], vb, oacc[n]);
      }
  }

  // normalize + store (bf16)
#pragma unroll
  for (int r = 0; r < 4; ++r) {
    float inv = 1.f / srow[r];
#pragma unroll
    for (int n = 0; n < 8; ++n) {
      size_t off = (size_t)(b * L_ + q0 + w * 16 + lg * 4 + r) * 2048 +
                   h * 128 + n * 16 + lr;
      O[off] = f2b(oacc[n][r] * inv);
    }
  }
}

// ---------------- launch ---------------------------------------------------
extern "C" void kernel_launch(void* const* d_in, const int* in_sizes, int n_in,
                              void* d_out, int out_size, void* d_ws, size_t ws_size,
                              hipStream_t stream) {
  const float* x    = (const float*)d_in[0];
  const float* ln1w = (const float*)d_in[1];
  const float* qw   = (const float*)d_in[2];
  const float* qb   = (const float*)d_in[3];
  const float* kw   = (const float*)d_in[4];
  const float* kb   = (const float*)d_in[5];
  const float* vw   = (const float*)d_in[6];
  const float* vbi  = (const float*)d_in[7];
  const float* ow   = (const float*)d_in[8];
  const float* ln2w = (const float*)d_in[9];
  const float* gw   = (const float*)d_in[10];
  const float* uw   = (const float*)d_in[11];
  const float* dw   = (const float*)d_in[12];
  float* out = (float*)d_out;

  char* ws = (char*)d_ws;
  u16* h    = (u16*)(ws);                  // 16 MiB
  u16* kbuf = (u16*)(ws + (16ull << 20));  // 4 MiB
  u16* vbuf = (u16*)(ws + (20ull << 20));  // 4 MiB
  u16* vt   = (u16*)(ws + (24ull << 20));  // 4 MiB
  u16* g    = (u16*)(ws + (16ull << 20));  // 11 MiB (phase C, reuses kb/vb)
  u16* qscr = (u16*)d_out;                 // bf16 Q scratch in d_out (16 MiB)

  dim3 blk(256);
  const bool big = ws_size >= 119537664ull;   // bf16-weight path needs ~114 MiB

  rmsnorm_k<<<MTOK, blk, 0, stream>>>(x, ln1w, h);

  if (big) {
    // bf16 weight pool at +28 MiB
    u16* wp = (u16*)(ws + (28ull << 20));
    u16* wq = wp;                          // 4,194,304 elems
    u16* wk = wq + 4194304;                // 1,048,576
    u16* wv = wk + 1048576;                // 1,048,576
    u16* wo = wv + 1048576;                // 4,194,304
    u16* wg = wo + 4194304;                // 11,534,336
    u16* wu = wg + 11534336;               // 11,534,336
    u16* wd = wu + 11534336;               // 11,534,336
    conv_k<<<2048, blk, 0, stream>>>(qw, wq, 4194304 / 8);
    conv_k<<<512, blk, 0, stream>>>(kw, wk, 1048576 / 8);
    conv_k<<<512, blk, 0, stream>>>(vw, wv, 1048576 / 8);
    conv_k<<<2048, blk, 0, stream>>>(ow, wo, 4194304 / 8);
    conv_k<<<2048, blk, 0, stream>>>(gw, wg, 11534336 / 8);
    conv_k<<<2048, blk, 0, stream>>>(uw, wu, 11534336 / 8);
    conv_k<<<2048, blk, 0, stream>>>(dw, wd, 11534336 / 8);

    gemm_bb<false><<<dim3(16, 32), blk, 0, stream>>>(h, D_, wq, D_, qb, nullptr, nullptr,
                                                     qscr, MTOK, 2048, 2048);
    gemm_bb<false><<<dim3(4, 32), blk, 0, stream>>>(h, D_, wk, D_, kb, nullptr, nullptr,
                                                    kbuf, MTOK, 512, 2048);
    gemm_bb<false><<<dim3(4, 32), blk, 0, stream>>>(h, D_, wv, D_, vbi, nullptr, nullptr,
                                                    vbuf, MTOK, 512, 2048);
    transpose_v<<<dim3(32, 2, 8), blk, 0, stream>>>(vbuf, vt);
    attn_k<<<dim3(32, 32), blk, 0, stream>>>(qscr, kbuf, vt, h);
    gemm_bb<true><<<dim3(16, 32), blk, 0, stream>>>(h, D_, wo, D_, nullptr, x, nullptr,
                                                    d_out, MTOK, 2048, 2048);
    rmsnorm_k<<<MTOK, blk, 0, stream>>>(out, ln2w, h);
    for (int fc = 0; fc < 4; ++fc) {
      const u16* gwc = wg + (size_t)fc * FC_ * D_;
      const u16* uwc = wu + (size_t)fc * FC_ * D_;
      const u16* dwc = wd + (size_t)fc * FC_;
      gemm_bb<false><<<dim3(11, 32), blk, 0, stream>>>(h, D_, gwc, D_, nullptr, nullptr,
                                                       nullptr, g, MTOK, FC_, 2048);
      gemm_bb<false><<<dim3(11, 32), blk, 0, stream>>>(h, D_, uwc, D_, nullptr, nullptr,
                                                       g, g, MTOK, FC_, 2048);
      gemm_bb<true><<<dim3(16, 32), blk, 0, stream>>>(g, FC_, dwc, F_, nullptr, out,
                                                      nullptr, d_out, MTOK, 2048, FC_);
    }
  } else {
    // fallback: fp32-weight register staging (round-4 proven path, 27 MiB)
    gemm_nt<false><<<dim3(16, 32), blk, 0, stream>>>(h, D_, qw, D_, qb, nullptr, nullptr,
                                                     qscr, MTOK, 2048, 2048);
    gemm_nt<false><<<dim3(4, 32), blk, 0, stream>>>(h, D_, kw, D_, kb, nullptr, nullptr,
                                                    kbuf, MTOK, 512, 2048);
    gemm_nt<false><<<dim3(4, 32), blk, 0, stream>>>(h, D_, vw, D_, vbi, nullptr, nullptr,
                                                    vbuf, MTOK, 512, 2048);
    transpose_v<<<dim3(32, 2, 8), blk, 0, stream>>>(vbuf, vt);
    attn_k<<<dim3(32, 32), blk, 0, stream>>>(qscr, kbuf, vt, h);
    gemm_nt<true><<<dim3(16, 32), blk, 0, stream>>>(h, D_, ow, D_, nullptr, x, nullptr,
                                                    d_out, MTOK, 2048, 2048);
    rmsnorm_k<<<MTOK, blk, 0, stream>>>(out, ln2w, h);
    for (int fc = 0; fc < 4; ++fc) {
      const float* gwc = gw + (size_t)fc * FC_ * D_;
      const float* uwc = uw + (size_t)fc * FC_ * D_;
      const float* dwc = dw + (size_t)fc * FC_;
      gemm_nt<false><<<dim3(11, 32), blk, 0, stream>>>(h, D_, gwc, D_, nullptr, nullptr,
                                                       nullptr, g, MTOK, FC_, 2048);
      gemm_nt<false><<<dim3(11, 32), blk, 0, stream>>>(h, D_, uwc, D_, nullptr, nullptr,
                                                       g, g, MTOK, FC_, 2048);
      gemm_nt<true><<<dim3(16, 32), blk, 0, stream>>>(g, FC_, dwc, F_, nullptr, out,
                                                      nullptr, d_out, MTOK, 2048, FC_);
    }
  }
}